// Round 8
// baseline (1362.478 us; speedup 1.0000x reference)
//
#include <hip/hip_runtime.h>
#include <math.h>

#define NROWS 8192
#define DIM   512
#define HID1  1024
#define HID2  512
#define NCLS  10
#define KTOP  64
#define KPACK 1024      // packed row: [hi(512) | lo(512)]
#define KFULL 1536      // logical GEMM K: hi*hi + hi*lo + lo*hi
#define EPSBAND 0.02f   // d2 ambiguity half-band; approx err <= ~2e-3

typedef __attribute__((ext_vector_type(8))) short short8;
typedef __attribute__((ext_vector_type(4))) float f32x4;
typedef __attribute__((ext_vector_type(4))) double f64x4;

__device__ __forceinline__ unsigned short f2bf(float x) {
    unsigned u = __float_as_uint(x);
    u += 0x7FFFu + ((u >> 16) & 1u);   // RN-even
    return (unsigned short)(u >> 16);
}
__device__ __forceinline__ float bf2f(unsigned short h) {
    return __uint_as_float(((unsigned)h) << 16);
}

// ---------------- column stats (mean/var over batch), fp64 ----------------
template <typename T>
__global__ __launch_bounds__(256) void col_stats_partial(
    const T* __restrict__ A, int F, int rowsPerBlock,
    double* __restrict__ pSum, double* __restrict__ pSqs)
{
    int c  = blockIdx.x * 256 + threadIdx.x;
    int r0 = blockIdx.y * rowsPerBlock;
    double s = 0.0, s2 = 0.0;
    for (int r = r0; r < r0 + rowsPerBlock; ++r) {
        double v = (double)A[(size_t)r * F + c];
        s  += v;
        s2 += v * v;
    }
    pSum[(size_t)blockIdx.y * F + c] = s;
    pSqs[(size_t)blockIdx.y * F + c] = s2;
}

__global__ __launch_bounds__(256) void col_stats_final(
    const double* __restrict__ pSum, const double* __restrict__ pSqs,
    const float* __restrict__ g, const float* __restrict__ b,
    double* __restrict__ scale, double* __restrict__ shift, int F, int nPart)
{
    int c = blockIdx.x * 256 + threadIdx.x;
    double s = 0.0, s2 = 0.0;
    for (int p = 0; p < nPart; ++p) {
        s  += pSum[(size_t)p * F + c];
        s2 += pSqs[(size_t)p * F + c];
    }
    double mean = s * (1.0 / NROWS);
    double var  = s2 * (1.0 / NROWS) - mean * mean;
    double sc   = (double)g[c] / sqrt(var + 1e-5);
    scale[c] = sc;
    shift[c] = (double)b[c] - mean * sc;
}

// ---------------- BN affine applied standalone (hoisted out of GEMMs) ----------------
__global__ __launch_bounds__(256) void bn_apply_f32(
    const float* __restrict__ x, const double* __restrict__ scl, const double* __restrict__ sft,
    double* __restrict__ out)   // 8192x512, fp32 -> fp64
{
    const int base = (blockIdx.x * 256 + threadIdx.x) * 4;
    float4 v = *(const float4*)&x[base];
    const int c = base & (DIM - 1);
    out[base + 0] = (double)v.x * scl[c + 0] + sft[c + 0];
    out[base + 1] = (double)v.y * scl[c + 1] + sft[c + 1];
    out[base + 2] = (double)v.z * scl[c + 2] + sft[c + 2];
    out[base + 3] = (double)v.w * scl[c + 3] + sft[c + 3];
}

__global__ __launch_bounds__(256) void bn_apply_f64(
    double* __restrict__ y, const double* __restrict__ scl, const double* __restrict__ sft,
    int mask)   // in-place, K = mask+1
{
    const int base = (blockIdx.x * 256 + threadIdx.x) * 4;
    const int c = base & mask;
    double2 v0 = *(const double2*)&y[base];
    double2 v1 = *(const double2*)&y[base + 2];
    v0.x = v0.x * scl[c + 0] + sft[c + 0];
    v0.y = v0.y * scl[c + 1] + sft[c + 1];
    v1.x = v1.x * scl[c + 2] + sft[c + 2];
    v1.y = v1.y * scl[c + 3] + sft[c + 3];
    *(double2*)&y[base]     = v0;
    *(double2*)&y[base + 2] = v1;
}

// ---------------- f64-MFMA: out = tanh( A @ W^T + bias ), pure fp64 GEMM ----------------
// Tile 128(M)x64(N), 4 waves, each wave 2 M-reps of 16x64. K-chunk 16, LDS DOUBLE-
// buffered (A fp64 33.8KB + B fp32 8.7KB = 42.5KB -> 3 blocks/CU), ONE barrier/chunk:
// issue loads(t+1) -> compute(t) -> ds_write(t+1 into nxt) -> barrier.
__global__ __launch_bounds__(256) void gemm_mfma_tanh(
    const double* __restrict__ A, const float* __restrict__ W, const float* __restrict__ bias,
    double* __restrict__ out, int Kd, int F)
{
    __shared__ double aS[2][16 * 132];
    __shared__ float  bS[2][16 * 68];
    const int t = threadIdx.x;
    const int lane = t & 63;
    const int wv = t >> 6;
    // bijective XCD swizzle (nwg divisible by 8)
    const int nwg = gridDim.x;
    const int q = nwg >> 3;
    const int bid = blockIdx.x;
    const int wgid = (bid & 7) * q + (bid >> 3);
    const int fBlocks = F >> 6;
    const int mb = wgid / fBlocks;
    const int fb = wgid - mb * fBlocks;
    const int fBase = fb * 64;
    const int mBase = mb * 128;
    const int arow = t >> 1;          // 0..127 (A M-row)
    const int akq  = (t & 1) * 8;     // A k offset 0/8
    const int wrow = t >> 2;          // 0..63 (W N-row)
    const int wkq  = (t & 3) * 4;     // W k offset 0/4/8/12

    f64x4 acc[2][4];
    #pragma unroll
    for (int p = 0; p < 2; ++p)
        #pragma unroll
        for (int n = 0; n < 4; ++n) acc[p][n] = (f64x4){0.0, 0.0, 0.0, 0.0};

    double areg[8];
    float  wreg[4];

    auto stage_load = [&](int ch) {
        const int kb = ch << 4;
        const double* ap = &A[(size_t)(mBase + arow) * Kd + kb + akq];
        #pragma unroll
        for (int j = 0; j < 4; ++j) {
            double2 v = *(const double2*)(ap + 2 * j);
            areg[2 * j] = v.x; areg[2 * j + 1] = v.y;
        }
        float4 w0 = *(const float4*)&W[(size_t)(fBase + wrow) * Kd + kb + wkq];
        wreg[0] = w0.x; wreg[1] = w0.y; wreg[2] = w0.z; wreg[3] = w0.w;
    };
    auto stage_write = [&](int buf) {
        #pragma unroll
        for (int i = 0; i < 8; ++i)
            aS[buf][(akq + i) * 132 + arow] = areg[i];
        #pragma unroll
        for (int i = 0; i < 4; ++i)
            bS[buf][(wkq + i) * 68 + wrow] = wreg[i];
    };
    auto compute = [&](int buf) {
        #pragma unroll
        for (int k4 = 0; k4 < 4; ++k4) {
            const int kk = k4 * 4 + (lane >> 4);
            double a0 = aS[buf][kk * 132 + wv * 16 + (lane & 15)];
            double a1 = aS[buf][kk * 132 + 64 + wv * 16 + (lane & 15)];
            #pragma unroll
            for (int n = 0; n < 4; ++n) {
                double b = (double)bS[buf][kk * 68 + n * 16 + (lane & 15)];
                acc[0][n] = __builtin_amdgcn_mfma_f64_16x16x4f64(a0, b, acc[0][n], 0, 0, 0);
                acc[1][n] = __builtin_amdgcn_mfma_f64_16x16x4f64(a1, b, acc[1][n], 0, 0, 0);
            }
        }
    };

    const int nChunks = Kd >> 4;
    stage_load(0);
    stage_write(0);
    __syncthreads();
    int cur = 0;
    for (int ch = 0; ch < nChunks; ++ch) {
        const bool hn = (ch + 1 < nChunks);
        if (hn) stage_load(ch + 1);    // VMEM in flight under the MFMA block
        compute(cur);
        if (hn) stage_write(cur ^ 1);  // other buffer: no wait on readers of cur
        __syncthreads();
        cur ^= 1;
    }

    // ---- epilogue: bias + tanh, fp64 store ----
    #pragma unroll
    for (int p = 0; p < 2; ++p) {
        #pragma unroll
        for (int n = 0; n < 4; ++n) {
            const int f = fBase + n * 16 + (lane & 15);
            const double bz = (double)bias[f];
            #pragma unroll
            for (int r = 0; r < 4; ++r) {
                const int m = mBase + p * 64 + wv * 16 + (lane >> 4) * 4 + r;
                out[(size_t)m * F + f] = tanh(acc[p][n][r] + bz);
            }
        }
    }
}

// ---------------- pack: f = y2*scl+sft (fp64) -> R=[hi|lo] bf16, sqf fp32 ----------------
__global__ __launch_bounds__(256) void pack_features(
    const double* __restrict__ y2, const double* __restrict__ scl, const double* __restrict__ sft,
    unsigned short* __restrict__ R, float* __restrict__ sqf)
{
    __shared__ double red[4];
    const int r = blockIdx.x;
    const int t = threadIdx.x;
    const int wid = t >> 6, lane = t & 63;
    const int c = t * 2;
    double2 y  = *(const double2*)&y2[(size_t)r * HID2 + c];
    double2 s2 = *(const double2*)&scl[c];
    double2 h2 = *(const double2*)&sft[c];
    double f0 = y.x * s2.x + h2.x;
    double f1 = y.y * s2.y + h2.y;
    unsigned short hi0 = f2bf((float)f0);
    unsigned short hi1 = f2bf((float)f1);
    unsigned short lo0 = f2bf((float)(f0 - (double)bf2f(hi0)));
    unsigned short lo1 = f2bf((float)(f1 - (double)bf2f(hi1)));
    unsigned short* Rr = R + (size_t)r * KPACK;
    Rr[c]           = hi0; Rr[c + 1]           = hi1;
    Rr[HID2 + c]    = lo0; Rr[HID2 + c + 1]    = lo1;
    double s = f0 * f0 + f1 * f1;
    #pragma unroll
    for (int off = 32; off > 0; off >>= 1) s += __shfl_down(s, off);
    if (lane == 0) red[wid] = s;
    __syncthreads();
    if (t == 0) sqf[r] = (float)(red[0] + red[1] + red[2] + red[3]);
}

// ---------------- sim chunk via bf16 MFMA: block 128x256, counted-vmcnt pipeline ----
// T4: STAGE(nxt) = 12 global_load_lds/wave; s_waitcnt vmcnt(12) waits only cur's
// loads (nxt's stay in flight across the barrier); raw s_barrier, no drain until the
// peeled last K-tile. T2 XOR swizzle via pre-swizzled global source + swizzled read.
__global__ __launch_bounds__(256, 1) void sim_mfma(
    const unsigned short* __restrict__ R, const float* __restrict__ sqf,
    float* __restrict__ simbuf, int rowBase)
{
    __shared__ unsigned short aT[2][128 * 64];
    __shared__ unsigned short bT[2][256 * 64];
    const int t = threadIdx.x;
    const int wid = t >> 6, lane = t & 63;
    const int wr = wid >> 1, wc = wid & 1;
    const int bid  = blockIdx.x;                    // 256 blocks = 1/CU
    const int wgid = (bid & 7) * 32 + (bid >> 3);   // XCD-contiguous chunks
    const int ib = wgid & 7;
    const int jb = wgid >> 3;
    const int iBase = rowBase + ib * 128;
    const int jBase = jb * 256;
    const int srow = lane >> 3;                     // 0..7 == row&7 at stage
    const int skk  = (((lane & 7) ^ srow) * 8);     // pre-swizzled 16B chunk in row

    f32x4 acc[4][8];
    #pragma unroll
    for (int m = 0; m < 4; ++m)
        #pragma unroll
        for (int n = 0; n < 8; ++n) acc[m][n] = (f32x4){0.f, 0.f, 0.f, 0.f};

    auto STAGE = [&](int buf, int kt) {
        const int k0 = kt * 64;
        const int aSrc = (k0 < 512)  ? k0 : (k0 - 512);   // [hi, hi, lo]
        const int bSrc = (k0 < 1024) ? k0 : (k0 - 1024);  // [hi, lo, hi]
        #pragma unroll
        for (int c = 0; c < 4; ++c) {                     // A: 4 instrs/wave
            const int g = wid * 4 + c;
            const unsigned short* gp = R + (size_t)(iBase + g * 8 + srow) * KPACK + aSrc + skk;
            __builtin_amdgcn_global_load_lds((const __attribute__((address_space(1))) void*)gp,
                (__attribute__((address_space(3))) void*)&aT[buf][g * 512], 16, 0, 0);
        }
        #pragma unroll
        for (int c = 0; c < 8; ++c) {                     // B: 8 instrs/wave
            const int g = wid * 8 + c;
            const unsigned short* gp = R + (size_t)(jBase + g * 8 + srow) * KPACK + bSrc + skk;
            __builtin_amdgcn_global_load_lds((const __attribute__((address_space(1))) void*)gp,
                (__attribute__((address_space(3))) void*)&bT[buf][g * 512], 16, 0, 0);
        }
    };
    auto MFMA_TILE = [&](int buf) {
        #pragma unroll
        for (int ks = 0; ks < 2; ++ks) {
            const int ck = ((ks * 4 + (lane >> 4)) ^ (lane & 7)) * 8;   // un-swizzle
            short8 aF[4], bF[8];
            #pragma unroll
            for (int m = 0; m < 4; ++m) {
                int rA = wr * 64 + m * 16 + (lane & 15);
                aF[m] = *(const short8*)&aT[buf][rA * 64 + ck];
            }
            #pragma unroll
            for (int n = 0; n < 8; ++n) {
                int rB = wc * 128 + n * 16 + (lane & 15);
                bF[n] = *(const short8*)&bT[buf][rB * 64 + ck];
            }
            __builtin_amdgcn_s_setprio(1);
            #pragma unroll
            for (int m = 0; m < 4; ++m)
                #pragma unroll
                for (int n = 0; n < 8; ++n)
                    acc[m][n] = __builtin_amdgcn_mfma_f32_16x16x32_bf16(aF[m], bF[n], acc[m][n], 0, 0, 0);
            __builtin_amdgcn_s_setprio(0);
        }
    };

    const int nKT = KFULL / 64;   // 24
    STAGE(0, 0);                  // 12 outstanding
    int cur = 0;
    for (int kt = 0; kt < nKT - 1; ++kt) {
        STAGE(cur ^ 1, kt + 1);                           // up to 24 outstanding
        asm volatile("s_waitcnt vmcnt(12)" ::: "memory"); // cur's 12 landed
        __builtin_amdgcn_s_barrier();                     // all waves' cur landed
        asm volatile("" ::: "memory");
        __builtin_amdgcn_sched_barrier(0);
        MFMA_TILE(cur);
        asm volatile("" ::: "memory");
        __builtin_amdgcn_s_barrier();                     // all done reading cur
        cur ^= 1;
    }
    asm volatile("s_waitcnt vmcnt(0)" ::: "memory");      // drain last tile
    __builtin_amdgcn_s_barrier();
    asm volatile("" ::: "memory");
    __builtin_amdgcn_sched_barrier(0);
    MFMA_TILE(cur);

    #pragma unroll
    for (int m = 0; m < 4; ++m) {
        #pragma unroll
        for (int n = 0; n < 8; ++n) {
            int j = jBase + wc * 128 + n * 16 + (lane & 15);
            float sqj = sqf[j];
            #pragma unroll
            for (int r = 0; r < 4; ++r) {
                int i = iBase + wr * 64 + m * 16 + (lane >> 4) * 4 + r;
                float d2 = sqf[i] + sqj - 2.0f * acc[m][n][r];
                d2 = fmaxf(d2, 0.f);
                float s = (i == j) ? -INFINITY : -d2;
                simbuf[(size_t)(i - rowBase) * NROWS + j] = s;
            }
        }
    }
}

// ---------------- top-K (fp32 rank) + fp64 band refinement + softmax ----------------
__device__ __forceinline__ unsigned fKey(float v) {
    unsigned b = __float_as_uint(v);
    return (b & 0x80000000u) ? ~b : (b | 0x80000000u);
}
__device__ __forceinline__ float keyToFloat(unsigned k) {
    unsigned b = (k & 0x80000000u) ? (k ^ 0x80000000u) : ~k;
    return __uint_as_float(b);
}

__global__ __launch_bounds__(256) void topk_refine(
    const float* __restrict__ simbuf,
    const double* __restrict__ y2, const double* __restrict__ scl, const double* __restrict__ sft,
    const int* __restrict__ labels, float* __restrict__ out, int rowBase)
{
    __shared__ unsigned redU[4], redL[4];
    __shared__ int      totArr[36];
    __shared__ float    redF[4];
    __shared__ float    cls[NCLS];
    __shared__ int      bandJ[128];
    __shared__ double   bandD2[128];
    __shared__ unsigned char keepB[128];
    __shared__ int      bandCnt;

    const int t = threadIdx.x;
    const int wid = t >> 6, lane = t & 63;
    const int row = blockIdx.x;
    const int gi = rowBase + row;
    const float* srow = simbuf + (size_t)row * NROWS;

    // load 32 keys via float4; key (ii,q) maps to column (t + ii*256)*4 + q
    unsigned key[32];
    #pragma unroll
    for (int ii = 0; ii < 8; ++ii) {
        float4 v = ((const float4*)srow)[t + ii * 256];
        key[ii * 4 + 0] = fKey(v.x);
        key[ii * 4 + 1] = fKey(v.y);
        key[ii * 4 + 2] = fKey(v.z);
        key[ii * 4 + 3] = fKey(v.w);
    }
    const unsigned infKey = fKey(-INFINITY);

    // row max/min keys (min excludes the -inf diagonal)
    unsigned kmax = 0u, kmin = 0xFFFFFFFFu;
    #pragma unroll
    for (int ii = 0; ii < 32; ++ii) {
        kmax = max(kmax, key[ii]);
        kmin = min(kmin, (key[ii] == infKey) ? 0xFFFFFFFFu : key[ii]);
    }
    #pragma unroll
    for (int off = 32; off > 0; off >>= 1) {
        kmax = max(kmax, (unsigned)__shfl_down(kmax, off));
        kmin = min(kmin, (unsigned)__shfl_down(kmin, off));
    }
    if (lane == 0) { redU[wid] = kmax; redL[wid] = kmin; }
    if (t == 0) bandCnt = 0;
    if (t < NCLS) cls[t] = 0.f;
    if (t < 36) totArr[t] = 0;
    __syncthreads();
    kmax = max(max(redU[0], redU[1]), max(redU[2], redU[3]));
    kmin = min(min(redL[0], redL[1]), min(redL[2], redL[3]));
    float d2min = fmaxf(-keyToFloat(kmax), 0.f);
    float distMin = (d2min > 1e-9f) ? sqrtf(d2min) : 0.f;

    // binary search in [kmin, kmax]: T64 = 64th largest key. One barrier per iter.
    unsigned lo = kmin, hi = kmax;
    int it = 0;
    while (lo < hi) {
        unsigned mid = lo + ((hi - lo + 1u) >> 1);
        int cnt = 0;
        #pragma unroll
        for (int ii = 0; ii < 32; ++ii) cnt += (key[ii] >= mid) ? 1 : 0;
        #pragma unroll
        for (int off = 32; off > 0; off >>= 1) cnt += __shfl_down(cnt, off);
        if (lane == 0) atomicAdd(&totArr[it], cnt);
        __syncthreads();
        int tot = totArr[it];
        if (tot >= KTOP) lo = mid; else hi = mid - 1u;
        ++it;
    }
    const float s64 = keyToFloat(lo);
    const unsigned Ku = fKey(s64 + EPSBAND);
    const unsigned Kl = fKey(s64 - EPSBAND);

    // nSafe = count(key >= Ku): definitely in true top-64
    {
        int cnt = 0;
        #pragma unroll
        for (int ii = 0; ii < 32; ++ii) cnt += (key[ii] >= Ku) ? 1 : 0;
        #pragma unroll
        for (int off = 32; off > 0; off >>= 1) cnt += __shfl_down(cnt, off);
        if (lane == 0) atomicAdd(&totArr[34], cnt);
    }
    // collect ambiguous band: Kl <= key < Ku
    #pragma unroll
    for (int ii = 0; ii < 8; ++ii) {
        #pragma unroll
        for (int q2 = 0; q2 < 4; ++q2) {
            unsigned k = key[ii * 4 + q2];
            if (k >= Kl && k < Ku) {
                int pos = atomicAdd(&bandCnt, 1);
                if (pos < 128) bandJ[pos] = (t + ii * 256) * 4 + q2;
            }
        }
    }
    __syncthreads();
    const int nSafe = totArr[34];
    const int Rslots = KTOP - nSafe;
    const int nb = min(bandCnt, 128);

    // exact fp64 d2 for band members (one wave per member)
    for (int c2 = wid; c2 < nb; c2 += 4) {
        int j = bandJ[c2];
        double s = 0.0;
        for (int d = lane; d < HID2; d += 64) {
            double sc = scl[d], sh = sft[d];
            double fi = y2[(size_t)gi * HID2 + d] * sc + sh;
            double fj = y2[(size_t)j  * HID2 + d] * sc + sh;
            double df = fi - fj;
            s += df * df;
        }
        #pragma unroll
        for (int off = 32; off > 0; off >>= 1) s += __shfl_down(s, off);
        if (lane == 0) bandD2[c2] = s;
    }
    __syncthreads();

    // rank band by (d2 asc, index asc); keep top Rslots
    for (int c2 = t; c2 < nb; c2 += 256) {
        double d2c = bandD2[c2];
        int jc = bandJ[c2];
        int rank = 0;
        for (int q2 = 0; q2 < nb; ++q2) {
            double dq = bandD2[q2];
            rank += (dq < d2c || (dq == d2c && bandJ[q2] < jc)) ? 1 : 0;
        }
        keepB[c2] = (rank < Rslots) ? 1 : 0;
    }
    __syncthreads();

    // softmax accumulate: safe set (fp32 d2) + kept band (fp64 d2)
    float S = 0.f;
    #pragma unroll
    for (int ii = 0; ii < 8; ++ii) {
        #pragma unroll
        for (int q2 = 0; q2 < 4; ++q2) {
            unsigned k = key[ii * 4 + q2];
            if (k >= Ku) {
                float d2 = -keyToFloat(k);
                float dist = (d2 > 1e-9f) ? sqrtf(d2) : 0.f;
                float w = expf(distMin - dist);
                S += w;
                atomicAdd(&cls[labels[(t + ii * 256) * 4 + q2]], w);
            }
        }
    }
    for (int c2 = t; c2 < nb; c2 += 256) {
        if (keepB[c2]) {
            double dd = bandD2[c2];
            float dist = (dd > 1e-9) ? (float)sqrt(dd) : 0.f;
            float w = expf(distMin - dist);
            S += w;
            atomicAdd(&cls[labels[bandJ[c2]]], w);
        }
    }
    #pragma unroll
    for (int off = 32; off > 0; off >>= 1) S += __shfl_down(S, off);
    if (lane == 0) redF[wid] = S;
    __syncthreads();
    float Stot = redF[0] + redF[1] + redF[2] + redF[3];

    if (t < NCLS) {
        float p = cls[t] / Stot;
        out[(size_t)gi * NCLS + t] = fminf(fmaxf(p, 0.f), 1.f);
    }
}

extern "C" void kernel_launch(void* const* d_in, const int* in_sizes, int n_in,
                              void* d_out, int out_size, void* d_ws, size_t ws_size,
                              hipStream_t stream)
{
    const float* x     = (const float*)d_in[0];
    // d_in[1] = x_n == x bit-exactly (self-neighbor mode) -> features computed once
    const int*   y_n   = (const int*)d_in[2];
    const float* ibn_g = (const float*)d_in[3];
    const float* ibn_b = (const float*)d_in[4];
    const float* W1    = (const float*)d_in[5];
    const float* b1    = (const float*)d_in[6];
    const float* g1    = (const float*)d_in[7];
    const float* bb1   = (const float*)d_in[8];
    const float* W2    = (const float*)d_in[9];
    const float* b2    = (const float*)d_in[10];
    const float* g2    = (const float*)d_in[11];
    const float* bb2   = (const float*)d_in[12];
    float* out = (float*)d_out;

    char* ws = (char*)d_ws;
    // [0,64 MiB): y1 fp64 during features; afterwards simbuf fp32 [0,32) + R bf16 [32,48)
    // [64,96 MiB): xbn fp64 during layer 1, then y2 fp64 (gemm2 overwrites; xbn dead)
    double*         y1   = (double*)(ws);
    float*          simb = (float*)(ws);
    unsigned short* Rp   = (unsigned short*)(ws + 33554432);
    double*         y2   = (double*)(ws + 67108864);        // 32 MiB (xbn alias)
    double*         xbn  = y2;
    double*         pSum = (double*)(ws + 100663296);       // 512 KiB
    double*         pSqs = (double*)(ws + 101187584);       // 512 KiB
    double*         prm  = (double*)(ws + 101711872);       // 6*1024 f64
    double* scale0 = prm;           double* shift0 = prm + 1024;
    double* scale1 = prm + 2048;    double* shift1 = prm + 3072;
    double* scale2 = prm + 4096;    double* shift2 = prm + 5120;
    float*          sqf  = (float*)(ws + 101761024);        // 8192 f32

    dim3 blk(256);
    const int RPB = NROWS / 64;

    // input BN params + apply (x fp32 -> xbn fp64)
    col_stats_partial<float><<<dim3(DIM / 256, 64), blk, 0, stream>>>(x, DIM, RPB, pSum, pSqs);
    col_stats_final<<<dim3(DIM / 256), blk, 0, stream>>>(pSum, pSqs, ibn_g, ibn_b, scale0, shift0, DIM, 64);
    bn_apply_f32<<<dim3(NROWS * DIM / 1024), blk, 0, stream>>>(x, scale0, shift0, xbn);
    // layer 1 (pure f64 MFMA GEMM)
    gemm_mfma_tanh<<<dim3((NROWS / 128) * (HID1 / 64)), blk, 0, stream>>>(xbn, W1, b1, y1, DIM, HID1);
    col_stats_partial<double><<<dim3(HID1 / 256, 64), blk, 0, stream>>>(y1, HID1, RPB, pSum, pSqs);
    col_stats_final<<<dim3(HID1 / 256), blk, 0, stream>>>(pSum, pSqs, g1, bb1, scale1, shift1, HID1, 64);
    bn_apply_f64<<<dim3(NROWS * HID1 / 1024), blk, 0, stream>>>(y1, scale1, shift1, HID1 - 1);
    // layer 2 (xbn dead; gemm2 writes y2 over it)
    gemm_mfma_tanh<<<dim3((NROWS / 128) * (HID2 / 64)), blk, 0, stream>>>(y1, W2, b2, y2, HID1, HID2);
    col_stats_partial<double><<<dim3(HID2 / 256, 64), blk, 0, stream>>>(y2, HID2, RPB, pSum, pSqs);
    col_stats_final<<<dim3(HID2 / 256), blk, 0, stream>>>(pSum, pSqs, g2, bb2, scale2, shift2, HID2, 64);
    // pack split-bf16 features + fp32 row norms (y1 now dead; R lives in its region)
    pack_features<<<dim3(NROWS), blk, 0, stream>>>(y2, scale2, shift2, Rp, sqf);
    // chunked MFMA sim + topk with fp64 band refinement
    for (int ch = 0; ch < 8; ++ch) {
        int rowBase = ch * 1024;
        sim_mfma<<<dim3(256), blk, 0, stream>>>(Rp, sqf, simb, rowBase);
        topk_refine<<<dim3(1024), blk, 0, stream>>>(simb, y2, scale2, shift2, y_n, out, rowBase);
    }
}

// Round 9
// 1275.600 us; speedup vs baseline: 1.0681x; 1.0681x over previous
//
#include <hip/hip_runtime.h>
#include <math.h>

#define NROWS 8192
#define DIM   512
#define HID1  1024
#define HID2  512
#define NCLS  10
#define KTOP  64
#define KPACK 1024      // packed row: [hi(512) | lo(512)]
#define KFULL 1536      // logical GEMM K: hi*hi + hi*lo + lo*hi
#define EPSBAND 0.02f   // d2 ambiguity half-band; approx err <= ~2e-3

typedef __attribute__((ext_vector_type(8))) short short8;
typedef __attribute__((ext_vector_type(4))) float f32x4;
typedef __attribute__((ext_vector_type(4))) double f64x4;

#define AS1 __attribute__((address_space(1)))
#define AS3 __attribute__((address_space(3)))

__device__ __forceinline__ unsigned short f2bf(float x) {
    unsigned u = __float_as_uint(x);
    u += 0x7FFFu + ((u >> 16) & 1u);   // RN-even
    return (unsigned short)(u >> 16);
}
__device__ __forceinline__ float bf2f(unsigned short h) {
    return __uint_as_float(((unsigned)h) << 16);
}

// ---------------- column stats (mean/var over batch), fp64 ----------------
template <typename T>
__global__ __launch_bounds__(256) void col_stats_partial(
    const T* __restrict__ A, int F, int rowsPerBlock,
    double* __restrict__ pSum, double* __restrict__ pSqs)
{
    int c  = blockIdx.x * 256 + threadIdx.x;
    int r0 = blockIdx.y * rowsPerBlock;
    double s = 0.0, s2 = 0.0;
    for (int r = r0; r < r0 + rowsPerBlock; ++r) {
        double v = (double)A[(size_t)r * F + c];
        s  += v;
        s2 += v * v;
    }
    pSum[(size_t)blockIdx.y * F + c] = s;
    pSqs[(size_t)blockIdx.y * F + c] = s2;
}

__global__ __launch_bounds__(256) void col_stats_final(
    const double* __restrict__ pSum, const double* __restrict__ pSqs,
    const float* __restrict__ g, const float* __restrict__ b,
    double* __restrict__ scale, double* __restrict__ shift, int F, int nPart)
{
    int c = blockIdx.x * 256 + threadIdx.x;
    double s = 0.0, s2 = 0.0;
    for (int p = 0; p < nPart; ++p) {
        s  += pSum[(size_t)p * F + c];
        s2 += pSqs[(size_t)p * F + c];
    }
    double mean = s * (1.0 / NROWS);
    double var  = s2 * (1.0 / NROWS) - mean * mean;
    double sc   = (double)g[c] / sqrt(var + 1e-5);
    scale[c] = sc;
    shift[c] = (double)b[c] - mean * sc;
}

// ---------------- BN affine applied standalone (hoisted out of GEMMs) ----------------
__global__ __launch_bounds__(256) void bn_apply_f32(
    const float* __restrict__ x, const double* __restrict__ scl, const double* __restrict__ sft,
    double* __restrict__ out)   // 8192x512, fp32 -> fp64
{
    const int base = (blockIdx.x * 256 + threadIdx.x) * 4;
    float4 v = *(const float4*)&x[base];
    const int c = base & (DIM - 1);
    out[base + 0] = (double)v.x * scl[c + 0] + sft[c + 0];
    out[base + 1] = (double)v.y * scl[c + 1] + sft[c + 1];
    out[base + 2] = (double)v.z * scl[c + 2] + sft[c + 2];
    out[base + 3] = (double)v.w * scl[c + 3] + sft[c + 3];
}

__global__ __launch_bounds__(256) void bn_apply_f64(
    double* __restrict__ y, const double* __restrict__ scl, const double* __restrict__ sft,
    int mask)   // in-place, K = mask+1
{
    const int base = (blockIdx.x * 256 + threadIdx.x) * 4;
    const int c = base & mask;
    double2 v0 = *(const double2*)&y[base];
    double2 v1 = *(const double2*)&y[base + 2];
    v0.x = v0.x * scl[c + 0] + sft[c + 0];
    v0.y = v0.y * scl[c + 1] + sft[c + 1];
    v1.x = v1.x * scl[c + 2] + sft[c + 2];
    v1.y = v1.y * scl[c + 3] + sft[c + 3];
    *(double2*)&y[base]     = v0;
    *(double2*)&y[base + 2] = v1;
}

// ---------------- f64-MFMA GEMM v3: out = tanh( A @ W^T + bias ) ----------------
// Tile 128(M)x64(N), 4 waves, K-chunk 32. Staging via global_load_lds (A fp64 16B=2
// doubles, B=W fp32 16B=4 floats), XOR-swizzled source (16B chunk c' = c ^ (row&7)),
// LDS double-buffered 2x(32+8)=80KB -> 2 blocks/CU. Counted-vmcnt pipeline:
// STAGE(nxt)[10 loads/wave] -> vmcnt(10) -> s_barrier -> MFMA(cur) -> s_barrier.
__global__ __launch_bounds__(256) void gemm_mfma_tanh(
    const double* __restrict__ A, const float* __restrict__ W, const float* __restrict__ bias,
    double* __restrict__ out, int Kd, int F)
{
    __shared__ double aD[2][128 * 32];
    __shared__ float  bD[2][64 * 32];
    const int t = threadIdx.x;
    const int lane = t & 63;
    const int wv = t >> 6;
    // bijective XCD swizzle (nwg divisible by 8)
    const int nwg = gridDim.x;
    const int q = nwg >> 3;
    const int bid = blockIdx.x;
    const int wgid = (bid & 7) * q + (bid >> 3);
    const int fBlocks = F >> 6;
    const int mb = wgid / fBlocks;
    const int fb = wgid - mb * fBlocks;
    const int fBase = fb * 64;
    const int mBase = mb * 128;

    f64x4 acc[2][4];
    #pragma unroll
    for (int p = 0; p < 2; ++p)
        #pragma unroll
        for (int n = 0; n < 4; ++n) acc[p][n] = (f64x4){0.0, 0.0, 0.0, 0.0};

    auto STAGE = [&](int buf, int ch) {
        const int kb = ch << 5;
        // A: 128 rows x 16 chunks(16B) = 2048 chunks; 8 instrs/wave
        #pragma unroll
        for (int i = 0; i < 8; ++i) {
            const int cid = (wv * 8 + i) * 64 + lane;
            const int row = cid >> 4, cl = cid & 15;
            const int cs = cl ^ (row & 7);
            const double* gp = &A[(size_t)(mBase + row) * Kd + kb + cs * 2];
            __builtin_amdgcn_global_load_lds((const AS1 void*)gp,
                (AS3 void*)&aD[buf][(wv * 8 + i) * 128], 16, 0, 0);
        }
        // B: 64 cols x 8 chunks(16B) = 512 chunks; 2 instrs/wave
        #pragma unroll
        for (int j = 0; j < 2; ++j) {
            const int cid = (wv * 2 + j) * 64 + lane;
            const int col = cid >> 3, cl = cid & 7;
            const int cs = cl ^ (col & 7);
            const float* gp = &W[(size_t)(fBase + col) * Kd + kb + cs * 4];
            __builtin_amdgcn_global_load_lds((const AS1 void*)gp,
                (AS3 void*)&bD[buf][(wv * 2 + j) * 256], 16, 0, 0);
        }
    };
    auto COMPUTE = [&](int buf) {
        #pragma unroll
        for (int k4 = 0; k4 < 8; ++k4) {
            const int kk = k4 * 4 + (lane >> 4);
            const int r0 = wv * 16 + (lane & 15);
            const int sw = ((kk >> 1) ^ (r0 & 7)) * 2 + (kk & 1);
            double a0 = aD[buf][r0 * 32 + sw];
            double a1 = aD[buf][(r0 + 64) * 32 + sw];
            #pragma unroll
            for (int n = 0; n < 4; ++n) {
                const int cl = n * 16 + (lane & 15);
                double b = (double)bD[buf][cl * 32 + ((kk >> 2) ^ (cl & 7)) * 4 + (kk & 3)];
                acc[0][n] = __builtin_amdgcn_mfma_f64_16x16x4f64(a0, b, acc[0][n], 0, 0, 0);
                acc[1][n] = __builtin_amdgcn_mfma_f64_16x16x4f64(a1, b, acc[1][n], 0, 0, 0);
            }
        }
    };

    const int nChunks = Kd >> 5;
    STAGE(0, 0);                                          // 10 outstanding
    int cur = 0;
    for (int ch = 0; ch < nChunks - 1; ++ch) {
        STAGE(cur ^ 1, ch + 1);                           // 20 outstanding
        asm volatile("s_waitcnt vmcnt(10)" ::: "memory"); // cur's 10 landed
        __builtin_amdgcn_s_barrier();                     // all waves' cur landed
        __builtin_amdgcn_sched_barrier(0);
        __builtin_amdgcn_s_setprio(1);
        COMPUTE(cur);
        __builtin_amdgcn_s_setprio(0);
        __builtin_amdgcn_s_barrier();                     // all done reading cur
        cur ^= 1;
    }
    asm volatile("s_waitcnt vmcnt(0)" ::: "memory");      // drain last chunk
    __builtin_amdgcn_s_barrier();
    __builtin_amdgcn_sched_barrier(0);
    COMPUTE(cur);

    // ---- epilogue: bias + tanh, fp64 store ----
    #pragma unroll
    for (int p = 0; p < 2; ++p) {
        #pragma unroll
        for (int n = 0; n < 4; ++n) {
            const int f = fBase + n * 16 + (lane & 15);
            const double bz = (double)bias[f];
            #pragma unroll
            for (int r = 0; r < 4; ++r) {
                const int m = mBase + p * 64 + wv * 16 + (lane >> 4) * 4 + r;
                out[(size_t)m * F + f] = tanh(acc[p][n][r] + bz);
            }
        }
    }
}

// ---------------- pack: f = y2*scl+sft (fp64) -> R=[hi|lo] bf16, sqf fp32 ----------------
__global__ __launch_bounds__(256) void pack_features(
    const double* __restrict__ y2, const double* __restrict__ scl, const double* __restrict__ sft,
    unsigned short* __restrict__ R, float* __restrict__ sqf)
{
    __shared__ double red[4];
    const int r = blockIdx.x;
    const int t = threadIdx.x;
    const int wid = t >> 6, lane = t & 63;
    const int c = t * 2;
    double2 y  = *(const double2*)&y2[(size_t)r * HID2 + c];
    double2 s2 = *(const double2*)&scl[c];
    double2 h2 = *(const double2*)&sft[c];
    double f0 = y.x * s2.x + h2.x;
    double f1 = y.y * s2.y + h2.y;
    unsigned short hi0 = f2bf((float)f0);
    unsigned short hi1 = f2bf((float)f1);
    unsigned short lo0 = f2bf((float)(f0 - (double)bf2f(hi0)));
    unsigned short lo1 = f2bf((float)(f1 - (double)bf2f(hi1)));
    unsigned short* Rr = R + (size_t)r * KPACK;
    Rr[c]           = hi0; Rr[c + 1]           = hi1;
    Rr[HID2 + c]    = lo0; Rr[HID2 + c + 1]    = lo1;
    double s = f0 * f0 + f1 * f1;
    #pragma unroll
    for (int off = 32; off > 0; off >>= 1) s += __shfl_down(s, off);
    if (lane == 0) red[wid] = s;
    __syncthreads();
    if (t == 0) sqf[r] = (float)(red[0] + red[1] + red[2] + red[3]);
}

// ---------------- sim chunk via bf16 MFMA: block 128x256, counted-vmcnt pipeline ----
__global__ __launch_bounds__(256, 1) void sim_mfma(
    const unsigned short* __restrict__ R, const float* __restrict__ sqf,
    float* __restrict__ simbuf, int rowBase)
{
    __shared__ unsigned short aT[2][128 * 64];
    __shared__ unsigned short bT[2][256 * 64];
    const int t = threadIdx.x;
    const int wid = t >> 6, lane = t & 63;
    const int wr = wid >> 1, wc = wid & 1;
    const int bid  = blockIdx.x;                    // 256 blocks = 1/CU
    const int wgid = (bid & 7) * 32 + (bid >> 3);   // XCD-contiguous chunks
    const int ib = wgid & 7;
    const int jb = wgid >> 3;
    const int iBase = rowBase + ib * 128;
    const int jBase = jb * 256;
    const int srow = lane >> 3;                     // 0..7 == row&7 at stage
    const int skk  = (((lane & 7) ^ srow) * 8);     // pre-swizzled 16B chunk in row

    f32x4 acc[4][8];
    #pragma unroll
    for (int m = 0; m < 4; ++m)
        #pragma unroll
        for (int n = 0; n < 8; ++n) acc[m][n] = (f32x4){0.f, 0.f, 0.f, 0.f};

    auto STAGE = [&](int buf, int kt) {
        const int k0 = kt * 64;
        const int aSrc = (k0 < 512)  ? k0 : (k0 - 512);   // [hi, hi, lo]
        const int bSrc = (k0 < 1024) ? k0 : (k0 - 1024);  // [hi, lo, hi]
        #pragma unroll
        for (int c = 0; c < 4; ++c) {                     // A: 4 instrs/wave
            const int g = wid * 4 + c;
            const unsigned short* gp = R + (size_t)(iBase + g * 8 + srow) * KPACK + aSrc + skk;
            __builtin_amdgcn_global_load_lds((const AS1 void*)gp,
                (AS3 void*)&aT[buf][g * 512], 16, 0, 0);
        }
        #pragma unroll
        for (int c = 0; c < 8; ++c) {                     // B: 8 instrs/wave
            const int g = wid * 8 + c;
            const unsigned short* gp = R + (size_t)(jBase + g * 8 + srow) * KPACK + bSrc + skk;
            __builtin_amdgcn_global_load_lds((const AS1 void*)gp,
                (AS3 void*)&bT[buf][g * 512], 16, 0, 0);
        }
    };
    auto MFMA_TILE = [&](int buf) {
        #pragma unroll
        for (int ks = 0; ks < 2; ++ks) {
            const int ck = ((ks * 4 + (lane >> 4)) ^ (lane & 7)) * 8;   // un-swizzle
            short8 aF[4], bF[8];
            #pragma unroll
            for (int m = 0; m < 4; ++m) {
                int rA = wr * 64 + m * 16 + (lane & 15);
                aF[m] = *(const short8*)&aT[buf][rA * 64 + ck];
            }
            #pragma unroll
            for (int n = 0; n < 8; ++n) {
                int rB = wc * 128 + n * 16 + (lane & 15);
                bF[n] = *(const short8*)&bT[buf][rB * 64 + ck];
            }
            __builtin_amdgcn_s_setprio(1);
            #pragma unroll
            for (int m = 0; m < 4; ++m)
                #pragma unroll
                for (int n = 0; n < 8; ++n)
                    acc[m][n] = __builtin_amdgcn_mfma_f32_16x16x32_bf16(aF[m], bF[n], acc[m][n], 0, 0, 0);
            __builtin_amdgcn_s_setprio(0);
        }
    };

    const int nKT = KFULL / 64;   // 24
    STAGE(0, 0);                  // 12 outstanding
    int cur = 0;
    for (int kt = 0; kt < nKT - 1; ++kt) {
        STAGE(cur ^ 1, kt + 1);                           // up to 24 outstanding
        asm volatile("s_waitcnt vmcnt(12)" ::: "memory"); // cur's 12 landed
        __builtin_amdgcn_s_barrier();                     // all waves' cur landed
        __builtin_amdgcn_sched_barrier(0);
        MFMA_TILE(cur);
        __builtin_amdgcn_s_barrier();                     // all done reading cur
        cur ^= 1;
    }
    asm volatile("s_waitcnt vmcnt(0)" ::: "memory");      // drain last tile
    __builtin_amdgcn_s_barrier();
    __builtin_amdgcn_sched_barrier(0);
    MFMA_TILE(cur);

    #pragma unroll
    for (int m = 0; m < 4; ++m) {
        #pragma unroll
        for (int n = 0; n < 8; ++n) {
            int j = jBase + wc * 128 + n * 16 + (lane & 15);
            float sqj = sqf[j];
            #pragma unroll
            for (int r = 0; r < 4; ++r) {
                int i = iBase + wr * 64 + m * 16 + (lane >> 4) * 4 + r;
                float d2 = sqf[i] + sqj - 2.0f * acc[m][n][r];
                d2 = fmaxf(d2, 0.f);
                float s = (i == j) ? -INFINITY : -d2;
                simbuf[(size_t)(i - rowBase) * NROWS + j] = s;
            }
        }
    }
}

// ---------------- top-K (fp32 rank) + fp64 band refinement + softmax ----------------
__device__ __forceinline__ unsigned fKey(float v) {
    unsigned b = __float_as_uint(v);
    return (b & 0x80000000u) ? ~b : (b | 0x80000000u);
}
__device__ __forceinline__ float keyToFloat(unsigned k) {
    unsigned b = (k & 0x80000000u) ? (k ^ 0x80000000u) : ~k;
    return __uint_as_float(b);
}

__global__ __launch_bounds__(256) void topk_refine(
    const float* __restrict__ simbuf,
    const double* __restrict__ y2, const double* __restrict__ scl, const double* __restrict__ sft,
    const int* __restrict__ labels, float* __restrict__ out, int rowBase)
{
    __shared__ unsigned redU[4], redL[4];
    __shared__ int      totArr[36];
    __shared__ float    redF[4];
    __shared__ float    cls[NCLS];
    __shared__ int      bandJ[128];
    __shared__ double   bandD2[128];
    __shared__ unsigned char keepB[128];
    __shared__ int      bandCnt;

    const int t = threadIdx.x;
    const int wid = t >> 6, lane = t & 63;
    const int row = blockIdx.x;
    const int gi = rowBase + row;
    const float* srow = simbuf + (size_t)row * NROWS;

    // load 32 keys via float4; key (ii,q) maps to column (t + ii*256)*4 + q
    unsigned key[32];
    #pragma unroll
    for (int ii = 0; ii < 8; ++ii) {
        float4 v = ((const float4*)srow)[t + ii * 256];
        key[ii * 4 + 0] = fKey(v.x);
        key[ii * 4 + 1] = fKey(v.y);
        key[ii * 4 + 2] = fKey(v.z);
        key[ii * 4 + 3] = fKey(v.w);
    }
    const unsigned infKey = fKey(-INFINITY);

    // row max/min keys (min excludes the -inf diagonal)
    unsigned kmax = 0u, kmin = 0xFFFFFFFFu;
    #pragma unroll
    for (int ii = 0; ii < 32; ++ii) {
        kmax = max(kmax, key[ii]);
        kmin = min(kmin, (key[ii] == infKey) ? 0xFFFFFFFFu : key[ii]);
    }
    #pragma unroll
    for (int off = 32; off > 0; off >>= 1) {
        kmax = max(kmax, (unsigned)__shfl_down(kmax, off));
        kmin = min(kmin, (unsigned)__shfl_down(kmin, off));
    }
    if (lane == 0) { redU[wid] = kmax; redL[wid] = kmin; }
    if (t == 0) bandCnt = 0;
    if (t < NCLS) cls[t] = 0.f;
    if (t < 36) totArr[t] = 0;
    __syncthreads();
    kmax = max(max(redU[0], redU[1]), max(redU[2], redU[3]));
    kmin = min(min(redL[0], redL[1]), min(redL[2], redL[3]));
    float d2min = fmaxf(-keyToFloat(kmax), 0.f);
    float distMin = (d2min > 1e-9f) ? sqrtf(d2min) : 0.f;

    // binary search in [kmin, kmax]: T64 = 64th largest key. One barrier per iter.
    unsigned lo = kmin, hi = kmax;
    int it = 0;
    while (lo < hi) {
        unsigned mid = lo + ((hi - lo + 1u) >> 1);
        int cnt = 0;
        #pragma unroll
        for (int ii = 0; ii < 32; ++ii) cnt += (key[ii] >= mid) ? 1 : 0;
        #pragma unroll
        for (int off = 32; off > 0; off >>= 1) cnt += __shfl_down(cnt, off);
        if (lane == 0) atomicAdd(&totArr[it], cnt);
        __syncthreads();
        int tot = totArr[it];
        if (tot >= KTOP) lo = mid; else hi = mid - 1u;
        ++it;
    }
    const float s64 = keyToFloat(lo);
    const unsigned Ku = fKey(s64 + EPSBAND);
    const unsigned Kl = fKey(s64 - EPSBAND);

    // nSafe = count(key >= Ku): definitely in true top-64
    {
        int cnt = 0;
        #pragma unroll
        for (int ii = 0; ii < 32; ++ii) cnt += (key[ii] >= Ku) ? 1 : 0;
        #pragma unroll
        for (int off = 32; off > 0; off >>= 1) cnt += __shfl_down(cnt, off);
        if (lane == 0) atomicAdd(&totArr[34], cnt);
    }
    // collect ambiguous band: Kl <= key < Ku
    #pragma unroll
    for (int ii = 0; ii < 8; ++ii) {
        #pragma unroll
        for (int q2 = 0; q2 < 4; ++q2) {
            unsigned k = key[ii * 4 + q2];
            if (k >= Kl && k < Ku) {
                int pos = atomicAdd(&bandCnt, 1);
                if (pos < 128) bandJ[pos] = (t + ii * 256) * 4 + q2;
            }
        }
    }
    __syncthreads();
    const int nSafe = totArr[34];
    const int Rslots = KTOP - nSafe;
    const int nb = min(bandCnt, 128);

    // exact fp64 d2 for band members (one wave per member)
    for (int c2 = wid; c2 < nb; c2 += 4) {
        int j = bandJ[c2];
        double s = 0.0;
        for (int d = lane; d < HID2; d += 64) {
            double sc = scl[d], sh = sft[d];
            double fi = y2[(size_t)gi * HID2 + d] * sc + sh;
            double fj = y2[(size_t)j  * HID2 + d] * sc + sh;
            double df = fi - fj;
            s += df * df;
        }
        #pragma unroll
        for (int off = 32; off > 0; off >>= 1) s += __shfl_down(s, off);
        if (lane == 0) bandD2[c2] = s;
    }
    __syncthreads();

    // rank band by (d2 asc, index asc); keep top Rslots
    for (int c2 = t; c2 < nb; c2 += 256) {
        double d2c = bandD2[c2];
        int jc = bandJ[c2];
        int rank = 0;
        for (int q2 = 0; q2 < nb; ++q2) {
            double dq = bandD2[q2];
            rank += (dq < d2c || (dq == d2c && bandJ[q2] < jc)) ? 1 : 0;
        }
        keepB[c2] = (rank < Rslots) ? 1 : 0;
    }
    __syncthreads();

    // softmax accumulate: safe set (fp32 d2) + kept band (fp64 d2)
    float S = 0.f;
    #pragma unroll
    for (int ii = 0; ii < 8; ++ii) {
        #pragma unroll
        for (int q2 = 0; q2 < 4; ++q2) {
            unsigned k = key[ii * 4 + q2];
            if (k >= Ku) {
                float d2 = -keyToFloat(k);
                float dist = (d2 > 1e-9f) ? sqrtf(d2) : 0.f;
                float w = expf(distMin - dist);
                S += w;
                atomicAdd(&cls[labels[(t + ii * 256) * 4 + q2]], w);
            }
        }
    }
    for (int c2 = t; c2 < nb; c2 += 256) {
        if (keepB[c2]) {
            double dd = bandD2[c2];
            float dist = (dd > 1e-9) ? (float)sqrt(dd) : 0.f;
            float w = expf(distMin - dist);
            S += w;
            atomicAdd(&cls[labels[bandJ[c2]]], w);
        }
    }
    #pragma unroll
    for (int off = 32; off > 0; off >>= 1) S += __shfl_down(S, off);
    if (lane == 0) redF[wid] = S;
    __syncthreads();
    float Stot = redF[0] + redF[1] + redF[2] + redF[3];

    if (t < NCLS) {
        float p = cls[t] / Stot;
        out[(size_t)gi * NCLS + t] = fminf(fmaxf(p, 0.f), 1.f);
    }
}

extern "C" void kernel_launch(void* const* d_in, const int* in_sizes, int n_in,
                              void* d_out, int out_size, void* d_ws, size_t ws_size,
                              hipStream_t stream)
{
    const float* x     = (const float*)d_in[0];
    // d_in[1] = x_n == x bit-exactly (self-neighbor mode) -> features computed once
    const int*   y_n   = (const int*)d_in[2];
    const float* ibn_g = (const float*)d_in[3];
    const float* ibn_b = (const float*)d_in[4];
    const float* W1    = (const float*)d_in[5];
    const float* b1    = (const float*)d_in[6];
    const float* g1    = (const float*)d_in[7];
    const float* bb1   = (const float*)d_in[8];
    const float* W2    = (const float*)d_in[9];
    const float* b2    = (const float*)d_in[10];
    const float* g2    = (const float*)d_in[11];
    const float* bb2   = (const float*)d_in[12];
    float* out = (float*)d_out;

    char* ws = (char*)d_ws;
    // [0,64 MiB): y1 fp64 during features; afterwards simbuf fp32 [0,32) + R bf16 [32,48)
    // [64,96 MiB): xbn fp64 during layer 1, then y2 fp64 (gemm2 overwrites; xbn dead)
    double*         y1   = (double*)(ws);
    float*          simb = (float*)(ws);
    unsigned short* Rp   = (unsigned short*)(ws + 33554432);
    double*         y2   = (double*)(ws + 67108864);        // 32 MiB (xbn alias)
    double*         xbn  = y2;
    double*         pSum = (double*)(ws + 100663296);       // 512 KiB
    double*         pSqs = (double*)(ws + 101187584);       // 512 KiB
    double*         prm  = (double*)(ws + 101711872);       // 6*1024 f64
    double* scale0 = prm;           double* shift0 = prm + 1024;
    double* scale1 = prm + 2048;    double* shift1 = prm + 3072;
    double* scale2 = prm + 4096;    double* shift2 = prm + 5120;
    float*          sqf  = (float*)(ws + 101761024);        // 8192 f32

    dim3 blk(256);
    const int RPB = NROWS / 64;

    // input BN params + apply (x fp32 -> xbn fp64)
    col_stats_partial<float><<<dim3(DIM / 256, 64), blk, 0, stream>>>(x, DIM, RPB, pSum, pSqs);
    col_stats_final<<<dim3(DIM / 256), blk, 0, stream>>>(pSum, pSqs, ibn_g, ibn_b, scale0, shift0, DIM, 64);
    bn_apply_f32<<<dim3(NROWS * DIM / 1024), blk, 0, stream>>>(x, scale0, shift0, xbn);
    // layer 1 (f64 MFMA GEMM v3)
    gemm_mfma_tanh<<<dim3((NROWS / 128) * (HID1 / 64)), blk, 0, stream>>>(xbn, W1, b1, y1, DIM, HID1);
    col_stats_partial<double><<<dim3(HID1 / 256, 64), blk, 0, stream>>>(y1, HID1, RPB, pSum, pSqs);
    col_stats_final<<<dim3(HID1 / 256), blk, 0, stream>>>(pSum, pSqs, g1, bb1, scale1, shift1, HID1, 64);
    bn_apply_f64<<<dim3(NROWS * HID1 / 1024), blk, 0, stream>>>(y1, scale1, shift1, HID1 - 1);
    // layer 2 (xbn dead; gemm2 writes y2 over it)
    gemm_mfma_tanh<<<dim3((NROWS / 128) * (HID2 / 64)), blk, 0, stream>>>(y1, W2, b2, y2, HID1, HID2);
    col_stats_partial<double><<<dim3(HID2 / 256, 64), blk, 0, stream>>>(y2, HID2, RPB, pSum, pSqs);
    col_stats_final<<<dim3(HID2 / 256), blk, 0, stream>>>(pSum, pSqs, g2, bb2, scale2, shift2, HID2, 64);
    // pack split-bf16 features + fp32 row norms (y1 now dead; R lives in its region)
    pack_features<<<dim3(NROWS), blk, 0, stream>>>(y2, scale2, shift2, Rp, sqf);
    // chunked MFMA sim + topk with fp64 band refinement
    for (int ch = 0; ch < 8; ++ch) {
        int rowBase = ch * 1024;
        sim_mfma<<<dim3(256), blk, 0, stream>>>(Rp, sqf, simb, rowBase);
        topk_refine<<<dim3(1024), blk, 0, stream>>>(simb, y2, scale2, shift2, y_n, out, rowBase);
    }
}